// Round 9
// baseline (1042.571 us; speedup 1.0000x reference)
//
#include <hip/hip_runtime.h>
#include <hip/hip_bf16.h>

#define VOCAB 32000
#define EMBED 512
#define HIDDEN 1024
#define NB 8
#define NT 256
#define XH_ROWS 16

#define NCH 8      // independent chains (= batch)
#define NMEM 32    // blocks per chain
#define RCOLS 32   // hidden columns per block

typedef __attribute__((ext_vector_type(8))) short bf16x8;
typedef __attribute__((ext_vector_type(4))) float f32x4;
typedef __attribute__((ext_vector_type(4))) unsigned u32x4;

__device__ __forceinline__ unsigned short bf16_bits(float f) {
    __hip_bfloat16 b = __float2bfloat16(f);
    unsigned short s;
    __builtin_memcpy(&s, &b, 2);
    return s;
}

// fast-path loads: bypass L1, hit the XCD-local L2 (sc0 only).
__device__ __forceinline__ void fast_load2(u32x4& q0, u32x4& q1,
                                           const unsigned long long* p0,
                                           const unsigned long long* p1) {
    asm volatile("global_load_dwordx4 %0, %2, off sc0\n\t"
                 "global_load_dwordx4 %1, %3, off sc0\n\t"
                 "s_waitcnt vmcnt(0)"
                 : "=&v"(q0), "=&v"(q1)
                 : "v"(p0), "v"(p1)
                 : "memory");
}
__device__ __forceinline__ void fast_load1(u32x4& q, const unsigned long long* p) {
    asm volatile("global_load_dwordx4 %0, %1, off sc0\n\ts_waitcnt vmcnt(0)"
                 : "=&v"(q) : "v"(p) : "memory");
}
__device__ __forceinline__ void agent_load(u32x4& q, const unsigned long long* p) {
    const unsigned long long a0 = __hip_atomic_load(p,     __ATOMIC_RELAXED, __HIP_MEMORY_SCOPE_AGENT);
    const unsigned long long a1 = __hip_atomic_load(p + 1, __ATOMIC_RELAXED, __HIP_MEMORY_SCOPE_AGENT);
    q.x = (unsigned)a0; q.y = (unsigned)(a0 >> 32);
    q.z = (unsigned)a1; q.w = (unsigned)(a1 >> 32);
}

// ---------------- W_hy [HIDDEN][VOCAB] f32 -> Wt [VOCAB][HIDDEN] bf16 ----------------
__global__ __launch_bounds__(256) void k_transpose(const float* __restrict__ W,
                                                   __hip_bfloat16* __restrict__ Wt) {
    __shared__ float tile[32][33];
    const int n0 = blockIdx.x * 32;
    const int k0 = blockIdx.y * 32;
    const int c = threadIdx.x & 31;
    const int r0 = threadIdx.x >> 5;
#pragma unroll
    for (int rr = 0; rr < 4; ++rr) {
        const int r = r0 + rr * 8;
        tile[c][r] = W[(size_t)(k0 + r) * VOCAB + n0 + c];
    }
    __syncthreads();
#pragma unroll
    for (int rr = 0; rr < 4; ++rr) {
        const int n = r0 + rr * 8;
        Wt[(size_t)(n0 + n) * HIDDEN + k0 + c] = __float2bfloat16(tile[n][c]);
    }
}

// ---------------- xh = emb[x] @ W_xh + b_h  (fp32) ----------------
__global__ __launch_bounds__(256) void k_xh(const int* __restrict__ ids,
                                            const float* __restrict__ emb,
                                            const float* __restrict__ Wxh,
                                            const float* __restrict__ bh,
                                            float* __restrict__ xh) {
    __shared__ alignas(16) float embS[XH_ROWS][EMBED];
    __shared__ int idsS[XH_ROWS];
    const int tid = threadIdx.x;
    const int blk = blockIdx.x;
    if (tid < XH_ROWS) idsS[tid] = ids[blk * XH_ROWS + tid];
    __syncthreads();
    const float4* emb4 = (const float4*)emb;
#pragma unroll
    for (int rep = 0; rep < (XH_ROWS * EMBED / 4) / 256; ++rep) {
        const int lin = rep * 256 + tid;
        const int r = lin >> 7;
        const int e4 = lin & 127;
        *(float4*)&embS[r][e4 * 4] = emb4[(size_t)idsS[r] * (EMBED / 4) + e4];
    }
    __syncthreads();
    float4 acc[XH_ROWS] = {};
    const float4* W4 = (const float4*)Wxh;
    for (int e = 0; e < EMBED; ++e) {
        const float4 w = W4[(size_t)e * (HIDDEN / 4) + tid];
#pragma unroll
        for (int r = 0; r < XH_ROWS; ++r) {
            const float ev = embS[r][e];
            acc[r].x += ev * w.x; acc[r].y += ev * w.y;
            acc[r].z += ev * w.z; acc[r].w += ev * w.w;
        }
    }
    const float4 bv = ((const float4*)bh)[tid];
#pragma unroll
    for (int r = 0; r < XH_ROWS; ++r) {
        float4 o;
        o.x = acc[r].x + bv.x; o.y = acc[r].y + bv.y;
        o.z = acc[r].z + bv.z; o.w = acc[r].w + bv.w;
        ((float4*)xh)[(size_t)(blk * XH_ROWS + r) * (HIDDEN / 4) + tid] = o;
    }
}

// ---------------- persistent recurrence: u64 token-in-data, dual-copy exchange ----------------
// Coherent copy (hxA): agent-scope atomics, always correct (cross-XCD via L3).
// Fast copy (hxF): plain stores + sc0 loads -> XCD-local L2 (works when all members
// of a chain share an XCD, i.e. bid%8 round-robin). Consumers try the fast copy 3x,
// then fall back to the coherent copy: correct under ANY block->XCD mapping.
// Double buffer + exact-token match is deadlock-free and replay-safe.
// Polling is done by waves 2-3 only (4 u64 words each, one combined vmcnt wait).
__global__ __launch_bounds__(256, 1) void k_rec(const float* __restrict__ Whh,
                                                const float* __restrict__ xh,
                                                unsigned long long* __restrict__ hxA,
                                                unsigned long long* __restrict__ hxF,
                                                __hip_bfloat16* __restrict__ hs) {
    __shared__ unsigned WstU[16 * 1040];   // part stride 1040 (==16 mod 32): W-read conflict-free
    __shared__ float xhS[NT * RCOLS];      // 32 KB, [t][col]
    __shared__ float hS[16 * 68];          // padded: elem e -> e + 4*(e>>6); bank = ii + 4*part
    __shared__ float red[16 * 33];
    const int tid = threadIdx.x;
    const int bid = blockIdx.x;
    const int c = bid & (NCH - 1);     // chain (bid%8 ~ XCD round robin)
    const int m = bid >> 3;            // member 0..31
    const int j0 = m * RCOLS;
    unsigned long long* hxcA = hxA + (size_t)c * 1024;   // [2][512] u64 words
    unsigned long long* hxcF = hxF + (size_t)c * 1024;

    // h_{-1} = 0 with token 0 lives in buf[1]; this member's 16 words, both copies
    if (tid < 16) {
        __hip_atomic_store(&hxcA[512 + m * 16 + tid], 0ull, __ATOMIC_RELAXED,
                           __HIP_MEMORY_SCOPE_AGENT);
        __hip_atomic_store(&hxcF[512 + m * 16 + tid], 0ull, __ATOMIC_RELAXED,
                           __HIP_MEMORY_SCOPE_WORKGROUP);
    }

    // pack W_hh slice: row i = part*64+ii, cols j0+2*col2, j0+2*col2+1
    for (int lin = tid; lin < 16 * 64 * 16; lin += 256) {
        const int part = lin >> 10;
        const int rem = lin & 1023;
        const int ii = rem >> 4;
        const int col2 = rem & 15;
        const int i = part * 64 + ii;
        const float2 w = *(const float2*)&Whh[(size_t)i * HIDDEN + j0 + 2 * col2];
        WstU[part * 1040 + ii * 16 + col2] =
            (unsigned)bf16_bits(w.x) | ((unsigned)bf16_bits(w.y) << 16);
    }
    // pre-stage this block's xh slice: [256][32]
    for (int idx = tid; idx < NT * RCOLS; idx += 256) {
        const int t = idx >> 5;
        const int col = idx & 31;
        xhS[idx] = xh[(size_t)(c * NT + t) * HIDDEN + j0 + col];
    }
    __syncthreads();

    const int col2 = tid & 15;
    const int part = tid >> 4;
    const unsigned* Wp = &WstU[part * 1040 + col2];
    const float* hp = &hS[part * 68];
    const int u = tid - 128;           // poll index for waves 2-3

    for (int t = 0; t < NT; ++t) {
        const int roff = ((t + 1) & 1) * 512;   // holds h_{t-1}, tokens == t
        const int woff = (t & 1) * 512;         // we write h_t, token t+1
        const unsigned tk = (unsigned)t;
        if (tid >= 128) {
            const unsigned long long* pF = hxcF + roff + 4 * u;
            const unsigned long long* pA = hxcA + roff + 4 * u;
            u32x4 q0, q1;
            fast_load2(q0, q1, pF, pF + 2);
            int tries = 0;
            while (true) {
                const bool miss0 = ((q0.x & 0xffffu) != tk) | ((q0.z & 0xffffu) != tk);
                const bool miss1 = ((q1.x & 0xffffu) != tk) | ((q1.z & 0xffffu) != tk);
                if (!(miss0 | miss1)) break;
                ++tries;
                if (tries <= 3) {
                    if (miss0) fast_load1(q0, pF);
                    if (miss1) fast_load1(q1, pF + 2);
                } else {
                    __builtin_amdgcn_s_sleep(1);
                    if (miss0) agent_load(q0, pA);
                    if (miss1) agent_load(q1, pA + 2);
                }
            }
            const int base = 8 * u + 4 * (u >> 3);   // padded hS index (stays in one 64-block)
            float4 f0, f1;
            f0.x = __uint_as_float(q0.x & 0xffff0000u);
            f0.y = __uint_as_float(q0.y << 16);
            f0.z = __uint_as_float(q0.z & 0xffff0000u);
            f0.w = __uint_as_float(q0.w << 16);
            f1.x = __uint_as_float(q1.x & 0xffff0000u);
            f1.y = __uint_as_float(q1.y << 16);
            f1.z = __uint_as_float(q1.z & 0xffff0000u);
            f1.w = __uint_as_float(q1.w << 16);
            *(float4*)&hS[base] = f0;
            *(float4*)&hS[base + 4] = f1;
        }
        __syncthreads();
        float a0 = 0.f, a1 = 0.f;
#pragma unroll 8
        for (int ii = 0; ii < 64; ++ii) {
            const unsigned w = Wp[ii * 16];
            const float hv = hp[ii];
            a0 = fmaf(__uint_as_float(w << 16), hv, a0);
            a1 = fmaf(__uint_as_float(w & 0xffff0000u), hv, a1);
        }
        red[part * 33 + 2 * col2]     = a0;
        red[part * 33 + 2 * col2 + 1] = a1;
        __syncthreads();
        if (tid < RCOLS) {
            float s = 0.f;
#pragma unroll
            for (int p = 0; p < 16; ++p) s += red[p * 33 + tid];
            const float v = tanhf(xhS[t * RCOLS + tid] + s);
            const unsigned hb = (unsigned)bf16_bits(v);
            ((unsigned short*)hs)[(size_t)(c * NT + t) * HIDDEN + j0 + tid] = (unsigned short)hb;
            const unsigned pb = (unsigned)__shfl_xor((int)hb, 1, 64);
            if ((tid & 1) == 0) {
                const unsigned long long wv = (unsigned long long)(unsigned)(t + 1)
                                            | ((unsigned long long)hb << 16)
                                            | ((unsigned long long)pb << 32);
                __hip_atomic_store(&hxcA[woff + m * 16 + (tid >> 1)], wv, __ATOMIC_RELAXED,
                                   __HIP_MEMORY_SCOPE_AGENT);
                __hip_atomic_store(&hxcF[woff + m * 16 + (tid >> 1)], wv, __ATOMIC_RELAXED,
                                   __HIP_MEMORY_SCOPE_WORKGROUP);
            }
        }
        // no trailing barrier: staging (waves 2-3) for step t+1 is gated by the token
        // poll, which can't pass until every member produced h_t (after sync #2).
    }
}

// ---------------- y = hs @ Wt^T + b_y  (bf16 MFMA, m97-style: global_load_lds) ----------------
__global__ __launch_bounds__(256) void k_proj(const __hip_bfloat16* __restrict__ A,   // [2048][1024]
                                              const __hip_bfloat16* __restrict__ Bt,  // [32000][1024]
                                              const float* __restrict__ by,
                                              float* __restrict__ C) {
    __shared__ __hip_bfloat16 At[128 * 32];    // linear: required by global_load_lds
    __shared__ __hip_bfloat16 Bts[128 * 32];
    const int tid = threadIdx.x;
    // bijective XCD-chunked swizzle (4000 % 8 == 0): consecutive swz ids (which
    // share a Bt 256KB panel, m-fastest) land on one XCD's L2.
    const int lin = blockIdx.x;
    const int swz = (lin & 7) * 500 + (lin >> 3);
    const int m0 = (swz & 15) * 128;
    const int n0 = (swz >> 4) * 128;
    const int lane = tid & 63;
    const int w = tid >> 6;
    const int wr = w >> 1, wc = w & 1;
    const int fr = lane & 15, fq = lane >> 4;
    f32x4 acc[4][4] = {};
    for (int k0 = 0; k0 < HIDDEN; k0 += 32) {
#pragma unroll
        for (int i = 0; i < 2; ++i) {
            const int ch = i * 256 + tid;
            const int row = ch >> 2, kq = (ch & 3) * 8;
            const __hip_bfloat16* ga = A  + (size_t)(m0 + row) * HIDDEN + k0 + kq;
            const __hip_bfloat16* gb = Bt + (size_t)(n0 + row) * HIDDEN + k0 + kq;
            __hip_bfloat16* la = At  + (size_t)((i * 256 + w * 64) * 8);
            __hip_bfloat16* lb = Bts + (size_t)((i * 256 + w * 64) * 8);
            __builtin_amdgcn_global_load_lds((const __attribute__((address_space(1))) unsigned*)ga,
                                             (__attribute__((address_space(3))) unsigned*)la, 16, 0, 0);
            __builtin_amdgcn_global_load_lds((const __attribute__((address_space(1))) unsigned*)gb,
                                             (__attribute__((address_space(3))) unsigned*)lb, 16, 0, 0);
        }
        __syncthreads();
        bf16x8 af[4], bfr[4];
#pragma unroll
        for (int mm = 0; mm < 4; ++mm)
            af[mm] = *(const bf16x8*)&At[(wr * 64 + mm * 16 + fr) * 32 + fq * 8];
#pragma unroll
        for (int nn = 0; nn < 4; ++nn)
            bfr[nn] = *(const bf16x8*)&Bts[(wc * 64 + nn * 16 + fr) * 32 + fq * 8];
#pragma unroll
        for (int mm = 0; mm < 4; ++mm)
#pragma unroll
            for (int nn = 0; nn < 4; ++nn)
                acc[mm][nn] = __builtin_amdgcn_mfma_f32_16x16x32_bf16(af[mm], bfr[nn], acc[mm][nn], 0, 0, 0);
        __syncthreads();
    }
#pragma unroll
    for (int nn = 0; nn < 4; ++nn) {
        const int col = n0 + wc * 64 + nn * 16 + fr;
        const float bias = by[col];
#pragma unroll
        for (int mm = 0; mm < 4; ++mm) {
            const int row = m0 + wr * 64 + mm * 16 + fq * 4;
            float* cp = C + (size_t)row * VOCAB + col;
            cp[0]                 = acc[mm][nn][0] + bias;
            cp[(size_t)VOCAB]     = acc[mm][nn][1] + bias;
            cp[(size_t)2 * VOCAB] = acc[mm][nn][2] + bias;
            cp[(size_t)3 * VOCAB] = acc[mm][nn][3] + bias;
        }
    }
}

extern "C" void kernel_launch(void* const* d_in, const int* in_sizes, int n_in,
                              void* d_out, int out_size, void* d_ws, size_t ws_size,
                              hipStream_t stream) {
    const int*   x   = (const int*)d_in[0];
    const float* emb = (const float*)d_in[1];
    const float* Wxh = (const float*)d_in[2];
    const float* Whh = (const float*)d_in[3];
    const float* bh  = (const float*)d_in[4];
    const float* Why = (const float*)d_in[5];
    const float* by  = (const float*)d_in[6];
    float* y = (float*)d_out;

    char* ws = (char*)d_ws;
    // layout: xh (8 MB) | hxA (64 KB) | hxF (64 KB) | hs bf16 (4 MB) | Wt bf16 (62.5 MB)
    const size_t off_xh  = 0;
    const size_t off_hxa = off_xh + (size_t)NB * NT * HIDDEN * 4;
    const size_t off_hxf = off_hxa + (size_t)NCH * 2 * 512 * 8;
    const size_t off_hs  = off_hxf + (size_t)NCH * 2 * 512 * 8;
    const size_t off_wt  = off_hs + (size_t)NB * NT * HIDDEN * 2;
    const size_t need    = off_wt + (size_t)VOCAB * HIDDEN * 2;
    if (ws_size < need) return;

    float* xh = (float*)(ws + off_xh);
    unsigned long long* hxA = (unsigned long long*)(ws + off_hxa);
    unsigned long long* hxF = (unsigned long long*)(ws + off_hxf);
    __hip_bfloat16* hs = (__hip_bfloat16*)(ws + off_hs);
    __hip_bfloat16* Wt = (__hip_bfloat16*)(ws + off_wt);

    k_xh<<<dim3((NB * NT) / XH_ROWS), 256, 0, stream>>>(x, emb, Wxh, bh, xh);
    k_transpose<<<dim3(VOCAB / 32, HIDDEN / 32), 256, 0, stream>>>(Why, Wt);
    k_rec<<<dim3(NCH * NMEM), 256, 0, stream>>>(Whh, xh, hxA, hxF, hs);
    k_proj<<<dim3((NB * NT / 128) * (VOCAB / 128)), 256, 0, stream>>>(hs, Wt, by, y);
}

// Round 10
// 830.165 us; speedup vs baseline: 1.2559x; 1.2559x over previous
//
#include <hip/hip_runtime.h>
#include <hip/hip_bf16.h>

#define VOCAB 32000
#define EMBED 512
#define HIDDEN 1024
#define NB 8
#define NT 256
#define XH_ROWS 16

#define NCH 8      // independent chains (= batch)
#define NMEM 32    // blocks per chain
#define RCOLS 32   // hidden columns per block

typedef __attribute__((ext_vector_type(8))) short bf16x8;
typedef __attribute__((ext_vector_type(4))) float f32x4;
typedef __attribute__((ext_vector_type(4))) unsigned u32x4;

__device__ __forceinline__ unsigned short bf16_bits(float f) {
    __hip_bfloat16 b = __float2bfloat16(f);
    unsigned short s;
    __builtin_memcpy(&s, &b, 2);
    return s;
}
__device__ __forceinline__ float lo16f(unsigned u) { return __uint_as_float(u << 16); }
__device__ __forceinline__ float hi16f(unsigned u) { return __uint_as_float(u & 0xffff0000u); }

// ---------------- W_hy [HIDDEN][VOCAB] f32 -> Wt [VOCAB][HIDDEN] bf16 ----------------
__global__ __launch_bounds__(256) void k_transpose(const float* __restrict__ W,
                                                   __hip_bfloat16* __restrict__ Wt) {
    __shared__ float tile[32][33];
    const int n0 = blockIdx.x * 32;
    const int k0 = blockIdx.y * 32;
    const int c = threadIdx.x & 31;
    const int r0 = threadIdx.x >> 5;
#pragma unroll
    for (int rr = 0; rr < 4; ++rr) {
        const int r = r0 + rr * 8;
        tile[c][r] = W[(size_t)(k0 + r) * VOCAB + n0 + c];
    }
    __syncthreads();
#pragma unroll
    for (int rr = 0; rr < 4; ++rr) {
        const int n = r0 + rr * 8;
        Wt[(size_t)(n0 + n) * HIDDEN + k0 + c] = __float2bfloat16(tile[n][c]);
    }
}

// ---------------- xh = emb[x] @ W_xh + b_h  (fp32) ----------------
__global__ __launch_bounds__(256) void k_xh(const int* __restrict__ ids,
                                            const float* __restrict__ emb,
                                            const float* __restrict__ Wxh,
                                            const float* __restrict__ bh,
                                            float* __restrict__ xh) {
    __shared__ alignas(16) float embS[XH_ROWS][EMBED];
    __shared__ int idsS[XH_ROWS];
    const int tid = threadIdx.x;
    const int blk = blockIdx.x;
    if (tid < XH_ROWS) idsS[tid] = ids[blk * XH_ROWS + tid];
    __syncthreads();
    const float4* emb4 = (const float4*)emb;
#pragma unroll
    for (int rep = 0; rep < (XH_ROWS * EMBED / 4) / 256; ++rep) {
        const int lin = rep * 256 + tid;
        const int r = lin >> 7;
        const int e4 = lin & 127;
        *(float4*)&embS[r][e4 * 4] = emb4[(size_t)idsS[r] * (EMBED / 4) + e4];
    }
    __syncthreads();
    float4 acc[XH_ROWS] = {};
    const float4* W4 = (const float4*)Wxh;
    for (int e = 0; e < EMBED; ++e) {
        const float4 w = W4[(size_t)e * (HIDDEN / 4) + tid];
#pragma unroll
        for (int r = 0; r < XH_ROWS; ++r) {
            const float ev = embS[r][e];
            acc[r].x += ev * w.x; acc[r].y += ev * w.y;
            acc[r].z += ev * w.z; acc[r].w += ev * w.w;
        }
    }
    const float4 bv = ((const float4*)bh)[tid];
#pragma unroll
    for (int r = 0; r < XH_ROWS; ++r) {
        float4 o;
        o.x = acc[r].x + bv.x; o.y = acc[r].y + bv.y;
        o.z = acc[r].z + bv.z; o.w = acc[r].w + bv.w;
        ((float4*)xh)[(size_t)(blk * XH_ROWS + r) * (HIDDEN / 4) + tid] = o;
    }
}

// ---------------- persistent recurrence: u64 token-in-data, W in REGISTERS ----------------
// One u64 = token(low16) | bf16 h[2w]<<16 | bf16 h[2w+1]<<32. Producers fire-and-forget
// relaxed agent stores; consumers poll 2 independent u64 per thread in one combined
// retry loop (round-8 protocol: the fastest measured). Double buffer + exact-token
// match is deadlock-free (induction over steps) and replay-safe (stale tokens
// 255/256 never match expected 0/1).
// This round: each thread's 64 packed W words are loop-invariant -> held in VGPRs.
// No W LDS array at all; per-step LDS traffic = 16 ds_read_b128 h reads.
__global__ __launch_bounds__(256, 1) void k_rec(const float* __restrict__ Whh,
                                                const float* __restrict__ xh,
                                                unsigned long long* __restrict__ hx,
                                                __hip_bfloat16* __restrict__ hs) {
    __shared__ float xhS[NT * RCOLS];      // 32 KB, [t][col]
    __shared__ float hS[16 * 68];          // padded: elem e -> e + 4*(e>>6); bank = ii + 4*part
    __shared__ float red[16 * 33];
    const int tid = threadIdx.x;
    const int bid = blockIdx.x;
    const int c = bid & (NCH - 1);     // chain (bid%8 ~ XCD round robin)
    const int m = bid >> 3;            // member 0..31
    const int j0 = m * RCOLS;
    unsigned long long* hxc = hx + (size_t)c * 1024;   // [2][512] u64 words

    // h_{-1} = 0 with token 0 lives in buf[1]; this member's 16 words
    if (tid < 16)
        __hip_atomic_store(&hxc[512 + m * 16 + tid], 0ull, __ATOMIC_RELAXED,
                           __HIP_MEMORY_SCOPE_AGENT);

    const int col2 = tid & 15;
    const int part = tid >> 4;

    // W slice into registers: thread (part,col2) covers rows part*64..+63,
    // cols {j0+2*col2, j0+2*col2+1}, packed 2 bf16 per u32.
    u32x4 wreg[16];
#pragma unroll
    for (int j = 0; j < 16; ++j) {
        u32x4 q;
#pragma unroll
        for (int e = 0; e < 4; ++e) {
            const int i = part * 64 + 4 * j + e;
            const float2 wv = *(const float2*)&Whh[(size_t)i * HIDDEN + j0 + 2 * col2];
            q[e] = (unsigned)bf16_bits(wv.x) | ((unsigned)bf16_bits(wv.y) << 16);
        }
        wreg[j] = q;
    }
    // pre-stage this block's xh slice: [256][32]
    for (int idx = tid; idx < NT * RCOLS; idx += 256) {
        const int t = idx >> 5;
        const int col = idx & 31;
        xhS[idx] = xh[(size_t)(c * NT + t) * HIDDEN + j0 + col];
    }
    __syncthreads();

    const f32x4* hv4 = (const f32x4*)&hS[part * 68];
    const int w0 = tid;          // u64 word indices this thread polls
    const int w1 = tid + 256;
    const int pe0 = 2 * tid + 4 * (tid >> 5);   // padded hS staging index

    for (int t = 0; t < NT; ++t) {
        unsigned long long* rbuf = hxc + ((t + 1) & 1) * 512;  // h_{t-1}, tokens == t
        unsigned long long* wbuf = hxc + (t & 1) * 512;        // we write h_t, token t+1
        const unsigned long long tok = (unsigned long long)(unsigned)t;
        // combined poll: both loads independent & in flight before the check
        unsigned long long a = __hip_atomic_load(&rbuf[w0], __ATOMIC_RELAXED, __HIP_MEMORY_SCOPE_AGENT);
        unsigned long long b = __hip_atomic_load(&rbuf[w1], __ATOMIC_RELAXED, __HIP_MEMORY_SCOPE_AGENT);
        while (((a & 0xffffull) != tok) | ((b & 0xffffull) != tok)) {
            __builtin_amdgcn_s_sleep(1);
            if ((a & 0xffffull) != tok)
                a = __hip_atomic_load(&rbuf[w0], __ATOMIC_RELAXED, __HIP_MEMORY_SCOPE_AGENT);
            if ((b & 0xffffull) != tok)
                b = __hip_atomic_load(&rbuf[w1], __ATOMIC_RELAXED, __HIP_MEMORY_SCOPE_AGENT);
        }
        *(float2*)&hS[pe0] = make_float2(__uint_as_float(((unsigned)(a >> 16) & 0xffffu) << 16),
                                         __uint_as_float(((unsigned)(a >> 32) & 0xffffu) << 16));
        *(float2*)&hS[pe0 + 544] = make_float2(__uint_as_float(((unsigned)(b >> 16) & 0xffffu) << 16),
                                               __uint_as_float(((unsigned)(b >> 32) & 0xffffu) << 16));
        __syncthreads();
        float a0 = 0.f, a1 = 0.f;
#pragma unroll
        for (int j = 0; j < 16; ++j) {
            const u32x4 w4 = wreg[j];
            const f32x4 h4 = hv4[j];
            a0 = fmaf(lo16f(w4.x), h4.x, a0); a1 = fmaf(hi16f(w4.x), h4.x, a1);
            a0 = fmaf(lo16f(w4.y), h4.y, a0); a1 = fmaf(hi16f(w4.y), h4.y, a1);
            a0 = fmaf(lo16f(w4.z), h4.z, a0); a1 = fmaf(hi16f(w4.z), h4.z, a1);
            a0 = fmaf(lo16f(w4.w), h4.w, a0); a1 = fmaf(hi16f(w4.w), h4.w, a1);
        }
        red[part * 33 + 2 * col2]     = a0;
        red[part * 33 + 2 * col2 + 1] = a1;
        __syncthreads();
        if (tid < RCOLS) {
            float s = 0.f;
#pragma unroll
            for (int p = 0; p < 16; ++p) s += red[p * 33 + tid];
            const float v = tanhf(xhS[t * RCOLS + tid] + s);
            const unsigned hb = (unsigned)bf16_bits(v);
            ((unsigned short*)hs)[(size_t)(c * NT + t) * HIDDEN + j0 + tid] = (unsigned short)hb;
            const unsigned pb = (unsigned)__shfl_xor((int)hb, 1, 64);
            if ((tid & 1) == 0) {
                const unsigned long long wv = (unsigned long long)(unsigned)(t + 1)
                                            | ((unsigned long long)hb << 16)
                                            | ((unsigned long long)pb << 32);
                __hip_atomic_store(&wbuf[m * 16 + (tid >> 1)], wv, __ATOMIC_RELAXED,
                                   __HIP_MEMORY_SCOPE_AGENT);
            }
        }
        // no trailing barrier: next step's hS staging is gated by the token poll,
        // which can't pass until every member produced h_t.
    }
}

// ---------------- y = hs @ Wt^T + b_y  (bf16 MFMA, m97-style: global_load_lds) ----------------
__global__ __launch_bounds__(256) void k_proj(const __hip_bfloat16* __restrict__ A,   // [2048][1024]
                                              const __hip_bfloat16* __restrict__ Bt,  // [32000][1024]
                                              const float* __restrict__ by,
                                              float* __restrict__ C) {
    __shared__ __hip_bfloat16 At[128 * 32];    // linear: required by global_load_lds
    __shared__ __hip_bfloat16 Bts[128 * 32];
    const int tid = threadIdx.x;
    // bijective XCD-chunked swizzle (4000 % 8 == 0): consecutive swz ids (which
    // share a Bt 256KB panel, m-fastest) land on one XCD's L2.
    const int lin = blockIdx.x;
    const int swz = (lin & 7) * 500 + (lin >> 3);
    const int m0 = (swz & 15) * 128;
    const int n0 = (swz >> 4) * 128;
    const int lane = tid & 63;
    const int w = tid >> 6;
    const int wr = w >> 1, wc = w & 1;
    const int fr = lane & 15, fq = lane >> 4;
    f32x4 acc[4][4] = {};
    for (int k0 = 0; k0 < HIDDEN; k0 += 32) {
#pragma unroll
        for (int i = 0; i < 2; ++i) {
            const int ch = i * 256 + tid;
            const int row = ch >> 2, kq = (ch & 3) * 8;
            const __hip_bfloat16* ga = A  + (size_t)(m0 + row) * HIDDEN + k0 + kq;
            const __hip_bfloat16* gb = Bt + (size_t)(n0 + row) * HIDDEN + k0 + kq;
            __hip_bfloat16* la = At  + (size_t)((i * 256 + w * 64) * 8);
            __hip_bfloat16* lb = Bts + (size_t)((i * 256 + w * 64) * 8);
            __builtin_amdgcn_global_load_lds((const __attribute__((address_space(1))) unsigned*)ga,
                                             (__attribute__((address_space(3))) unsigned*)la, 16, 0, 0);
            __builtin_amdgcn_global_load_lds((const __attribute__((address_space(1))) unsigned*)gb,
                                             (__attribute__((address_space(3))) unsigned*)lb, 16, 0, 0);
        }
        __syncthreads();
        bf16x8 af[4], bfr[4];
#pragma unroll
        for (int mm = 0; mm < 4; ++mm)
            af[mm] = *(const bf16x8*)&At[(wr * 64 + mm * 16 + fr) * 32 + fq * 8];
#pragma unroll
        for (int nn = 0; nn < 4; ++nn)
            bfr[nn] = *(const bf16x8*)&Bts[(wc * 64 + nn * 16 + fr) * 32 + fq * 8];
#pragma unroll
        for (int mm = 0; mm < 4; ++mm)
#pragma unroll
            for (int nn = 0; nn < 4; ++nn)
                acc[mm][nn] = __builtin_amdgcn_mfma_f32_16x16x32_bf16(af[mm], bfr[nn], acc[mm][nn], 0, 0, 0);
        __syncthreads();
    }
#pragma unroll
    for (int nn = 0; nn < 4; ++nn) {
        const int col = n0 + wc * 64 + nn * 16 + fr;
        const float bias = by[col];
#pragma unroll
        for (int mm = 0; mm < 4; ++mm) {
            const int row = m0 + wr * 64 + mm * 16 + fq * 4;
            float* cp = C + (size_t)row * VOCAB + col;
            cp[0]                 = acc[mm][nn][0] + bias;
            cp[(size_t)VOCAB]     = acc[mm][nn][1] + bias;
            cp[(size_t)2 * VOCAB] = acc[mm][nn][2] + bias;
            cp[(size_t)3 * VOCAB] = acc[mm][nn][3] + bias;
        }
    }
}

extern "C" void kernel_launch(void* const* d_in, const int* in_sizes, int n_in,
                              void* d_out, int out_size, void* d_ws, size_t ws_size,
                              hipStream_t stream) {
    const int*   x   = (const int*)d_in[0];
    const float* emb = (const float*)d_in[1];
    const float* Wxh = (const float*)d_in[2];
    const float* Whh = (const float*)d_in[3];
    const float* bh  = (const float*)d_in[4];
    const float* Why = (const float*)d_in[5];
    const float* by  = (const float*)d_in[6];
    float* y = (float*)d_out;

    char* ws = (char*)d_ws;
    // layout: xh (8 MB) | hx u64[8][2][512] (64 KB) | hs bf16 (4 MB) | Wt bf16 (62.5 MB)
    const size_t off_xh = 0;
    const size_t off_hx = off_xh + (size_t)NB * NT * HIDDEN * 4;
    const size_t off_hs = off_hx + (size_t)NCH * 2 * 512 * 8;
    const size_t off_wt = off_hs + (size_t)NB * NT * HIDDEN * 2;
    const size_t need   = off_wt + (size_t)VOCAB * HIDDEN * 2;
    if (ws_size < need) return;

    float* xh = (float*)(ws + off_xh);
    unsigned long long* hx = (unsigned long long*)(ws + off_hx);
    __hip_bfloat16* hs = (__hip_bfloat16*)(ws + off_hs);
    __hip_bfloat16* Wt = (__hip_bfloat16*)(ws + off_wt);

    k_xh<<<dim3((NB * NT) / XH_ROWS), 256, 0, stream>>>(x, emb, Wxh, bh, xh);
    k_transpose<<<dim3(VOCAB / 32, HIDDEN / 32), 256, 0, stream>>>(Why, Wt);
    k_rec<<<dim3(NCH * NMEM), 256, 0, stream>>>(Whh, xh, hx, hs);
    k_proj<<<dim3((NB * NT / 128) * (VOCAB / 128)), 256, 0, stream>>>(hs, Wt, by, y);
}

// Round 12
// 803.685 us; speedup vs baseline: 1.2972x; 1.0329x over previous
//
#include <hip/hip_runtime.h>
#include <hip/hip_bf16.h>

#define VOCAB 32000
#define EMBED 512
#define HIDDEN 1024
#define NB 8
#define NT 256
#define XH_ROWS 16

#define NCH 8      // independent chains (= batch)
#define NMEM 32    // blocks per chain
#define RCOLS 32   // hidden columns per block

typedef __attribute__((ext_vector_type(8))) short bf16x8;
typedef __attribute__((ext_vector_type(4))) float f32x4;
typedef __attribute__((ext_vector_type(4))) unsigned u32x4;

#define AS1 __attribute__((address_space(1)))
#define AS3 __attribute__((address_space(3)))

__device__ __forceinline__ unsigned short bf16_bits(float f) {
    __hip_bfloat16 b = __float2bfloat16(f);
    unsigned short s;
    __builtin_memcpy(&s, &b, 2);
    return s;
}
__device__ __forceinline__ float lo16f(unsigned u) { return __uint_as_float(u << 16); }
__device__ __forceinline__ float hi16f(unsigned u) { return __uint_as_float(u & 0xffff0000u); }

// ---------------- W_hy [HIDDEN][VOCAB] f32 -> Wt [VOCAB][HIDDEN] bf16 ----------------
__global__ __launch_bounds__(256) void k_transpose(const float* __restrict__ W,
                                                   __hip_bfloat16* __restrict__ Wt) {
    __shared__ float tile[32][33];
    const int n0 = blockIdx.x * 32;
    const int k0 = blockIdx.y * 32;
    const int c = threadIdx.x & 31;
    const int r0 = threadIdx.x >> 5;
#pragma unroll
    for (int rr = 0; rr < 4; ++rr) {
        const int r = r0 + rr * 8;
        tile[c][r] = W[(size_t)(k0 + r) * VOCAB + n0 + c];
    }
    __syncthreads();
#pragma unroll
    for (int rr = 0; rr < 4; ++rr) {
        const int n = r0 + rr * 8;
        Wt[(size_t)(n0 + n) * HIDDEN + k0 + c] = __float2bfloat16(tile[n][c]);
    }
}

// ---------------- xh = emb[x] @ W_xh + b_h  (fp32) ----------------
__global__ __launch_bounds__(256) void k_xh(const int* __restrict__ ids,
                                            const float* __restrict__ emb,
                                            const float* __restrict__ Wxh,
                                            const float* __restrict__ bh,
                                            float* __restrict__ xh) {
    __shared__ alignas(16) float embS[XH_ROWS][EMBED];
    __shared__ int idsS[XH_ROWS];
    const int tid = threadIdx.x;
    const int blk = blockIdx.x;
    if (tid < XH_ROWS) idsS[tid] = ids[blk * XH_ROWS + tid];
    __syncthreads();
    const float4* emb4 = (const float4*)emb;
#pragma unroll
    for (int rep = 0; rep < (XH_ROWS * EMBED / 4) / 256; ++rep) {
        const int lin = rep * 256 + tid;
        const int r = lin >> 7;
        const int e4 = lin & 127;
        *(float4*)&embS[r][e4 * 4] = emb4[(size_t)idsS[r] * (EMBED / 4) + e4];
    }
    __syncthreads();
    float4 acc[XH_ROWS] = {};
    const float4* W4 = (const float4*)Wxh;
    for (int e = 0; e < EMBED; ++e) {
        const float4 w = W4[(size_t)e * (HIDDEN / 4) + tid];
#pragma unroll
        for (int r = 0; r < XH_ROWS; ++r) {
            const float ev = embS[r][e];
            acc[r].x += ev * w.x; acc[r].y += ev * w.y;
            acc[r].z += ev * w.z; acc[r].w += ev * w.w;
        }
    }
    const float4 bv = ((const float4*)bh)[tid];
#pragma unroll
    for (int r = 0; r < XH_ROWS; ++r) {
        float4 o;
        o.x = acc[r].x + bv.x; o.y = acc[r].y + bv.y;
        o.z = acc[r].z + bv.z; o.w = acc[r].w + bv.w;
        ((float4*)xh)[(size_t)(blk * XH_ROWS + r) * (HIDDEN / 4) + tid] = o;
    }
}

// ---------------- persistent recurrence: u64 token-in-data, W in REGISTERS ----------------
// (unchanged from round 10: 447 us, conflicts 0)
__global__ __launch_bounds__(256, 1) void k_rec(const float* __restrict__ Whh,
                                                const float* __restrict__ xh,
                                                unsigned long long* __restrict__ hx,
                                                __hip_bfloat16* __restrict__ hs) {
    __shared__ float xhS[NT * RCOLS];      // 32 KB, [t][col]
    __shared__ float hS[16 * 68];          // padded: elem e -> e + 4*(e>>6); bank = ii + 4*part
    __shared__ float red[16 * 33];
    const int tid = threadIdx.x;
    const int bid = blockIdx.x;
    const int c = bid & (NCH - 1);
    const int m = bid >> 3;
    const int j0 = m * RCOLS;
    unsigned long long* hxc = hx + (size_t)c * 1024;

    if (tid < 16)
        __hip_atomic_store(&hxc[512 + m * 16 + tid], 0ull, __ATOMIC_RELAXED,
                           __HIP_MEMORY_SCOPE_AGENT);

    const int col2 = tid & 15;
    const int part = tid >> 4;

    u32x4 wreg[16];
#pragma unroll
    for (int j = 0; j < 16; ++j) {
        u32x4 q;
#pragma unroll
        for (int e = 0; e < 4; ++e) {
            const int i = part * 64 + 4 * j + e;
            const float2 wv = *(const float2*)&Whh[(size_t)i * HIDDEN + j0 + 2 * col2];
            q[e] = (unsigned)bf16_bits(wv.x) | ((unsigned)bf16_bits(wv.y) << 16);
        }
        wreg[j] = q;
    }
    for (int idx = tid; idx < NT * RCOLS; idx += 256) {
        const int t = idx >> 5;
        const int col = idx & 31;
        xhS[idx] = xh[(size_t)(c * NT + t) * HIDDEN + j0 + col];
    }
    __syncthreads();

    const f32x4* hv4 = (const f32x4*)&hS[part * 68];
    const int w0 = tid;
    const int w1 = tid + 256;
    const int pe0 = 2 * tid + 4 * (tid >> 5);

    for (int t = 0; t < NT; ++t) {
        unsigned long long* rbuf = hxc + ((t + 1) & 1) * 512;
        unsigned long long* wbuf = hxc + (t & 1) * 512;
        const unsigned long long tok = (unsigned long long)(unsigned)t;
        unsigned long long a = __hip_atomic_load(&rbuf[w0], __ATOMIC_RELAXED, __HIP_MEMORY_SCOPE_AGENT);
        unsigned long long b = __hip_atomic_load(&rbuf[w1], __ATOMIC_RELAXED, __HIP_MEMORY_SCOPE_AGENT);
        while (((a & 0xffffull) != tok) | ((b & 0xffffull) != tok)) {
            __builtin_amdgcn_s_sleep(1);
            if ((a & 0xffffull) != tok)
                a = __hip_atomic_load(&rbuf[w0], __ATOMIC_RELAXED, __HIP_MEMORY_SCOPE_AGENT);
            if ((b & 0xffffull) != tok)
                b = __hip_atomic_load(&rbuf[w1], __ATOMIC_RELAXED, __HIP_MEMORY_SCOPE_AGENT);
        }
        *(float2*)&hS[pe0] = make_float2(__uint_as_float(((unsigned)(a >> 16) & 0xffffu) << 16),
                                         __uint_as_float(((unsigned)(a >> 32) & 0xffffu) << 16));
        *(float2*)&hS[pe0 + 544] = make_float2(__uint_as_float(((unsigned)(b >> 16) & 0xffffu) << 16),
                                               __uint_as_float(((unsigned)(b >> 32) & 0xffffu) << 16));
        __syncthreads();
        float a0 = 0.f, a1 = 0.f;
#pragma unroll
        for (int j = 0; j < 16; ++j) {
            const u32x4 w4 = wreg[j];
            const f32x4 h4 = hv4[j];
            a0 = fmaf(lo16f(w4.x), h4.x, a0); a1 = fmaf(hi16f(w4.x), h4.x, a1);
            a0 = fmaf(lo16f(w4.y), h4.y, a0); a1 = fmaf(hi16f(w4.y), h4.y, a1);
            a0 = fmaf(lo16f(w4.z), h4.z, a0); a1 = fmaf(hi16f(w4.z), h4.z, a1);
            a0 = fmaf(lo16f(w4.w), h4.w, a0); a1 = fmaf(hi16f(w4.w), h4.w, a1);
        }
        red[part * 33 + 2 * col2]     = a0;
        red[part * 33 + 2 * col2 + 1] = a1;
        __syncthreads();
        if (tid < RCOLS) {
            float s = 0.f;
#pragma unroll
            for (int p = 0; p < 16; ++p) s += red[p * 33 + tid];
            const float v = tanhf(xhS[t * RCOLS + tid] + s);
            const unsigned hb = (unsigned)bf16_bits(v);
            ((unsigned short*)hs)[(size_t)(c * NT + t) * HIDDEN + j0 + tid] = (unsigned short)hb;
            const unsigned pb = (unsigned)__shfl_xor((int)hb, 1, 64);
            if ((tid & 1) == 0) {
                const unsigned long long wv = (unsigned long long)(unsigned)(t + 1)
                                            | ((unsigned long long)hb << 16)
                                            | ((unsigned long long)pb << 32);
                __hip_atomic_store(&wbuf[m * 16 + (tid >> 1)], wv, __ATOMIC_RELAXED,
                                   __HIP_MEMORY_SCOPE_AGENT);
            }
        }
    }
}

// ---------------- y = hs @ Wt^T + b_y : 256x256 tile, counted-vmcnt pipeline ----------------
// 512 thr (2x4 waves, 128x64 per wave), BK=64, LDS 128KB double-buffered.
// Staging: global_load_lds linear dest + inverse-XOR global source; reads XOR slot
// by (row&7) -> 2-way residual conflict (free). Raw s_barrier only (no vmcnt drain);
// vmcnt(8) keeps next K-tile's 8 loads in flight across barriers; setprio around MFMA.
// FIX r12: k-slice slot index is ks*4 + fq (8 slots/row), was ks*2 + fq.
__global__ __launch_bounds__(512, 2) void k_proj(const unsigned short* __restrict__ A,   // [2048][1024]
                                                 const unsigned short* __restrict__ Bt,  // [32000][1024]
                                                 const float* __restrict__ by,
                                                 float* __restrict__ C) {
    __shared__ unsigned short LDS[4][16384];   // [buf*2+mat][256*64] bf16
    const int tid = threadIdx.x;
    const int wid = tid >> 6;
    const int lane = tid & 63;
    const int lin = blockIdx.x;
    // bijective XCD swizzle (1000 % 8 == 0), mt fastest within an XCD chunk
    const int swz = (lin & 7) * 125 + (lin >> 3);
    const int mt = swz & 7, nt = swz >> 3;
    const int m0 = mt * 256, n0 = nt * 256;
    const int wr = wid >> 2, wc = wid & 3;     // 2 x 4 wave grid
    const int fr = lane & 15, fq = lane >> 4;
    const int srow = tid >> 3;                 // staging row within 64-row j-block
    const int sslot = tid & 7;                 // staging 16B slot (physical)

    f32x4 acc[8][4] = {};

#define STAGE(kt, bf)                                                                     \
    {                                                                                     \
        const unsigned short* Ag = A + (size_t)m0 * HIDDEN + (size_t)(kt) * 64;           \
        const unsigned short* Bg = Bt + (size_t)n0 * HIDDEN + (size_t)(kt) * 64;          \
        _Pragma("unroll")                                                                 \
        for (int j = 0; j < 4; ++j) {                                                     \
            const int r = j * 64 + srow;                                                  \
            const int ls = ((sslot ^ (r & 7)) * 8);                                       \
            __builtin_amdgcn_global_load_lds(                                             \
                (const AS1 unsigned*)(Ag + (size_t)r * HIDDEN + ls),                      \
                (AS3 unsigned*)(&LDS[(bf) * 2 + 0][j * 4096 + wid * 512]), 16, 0, 0);     \
        }                                                                                 \
        _Pragma("unroll")                                                                 \
        for (int j = 0; j < 4; ++j) {                                                     \
            const int r = j * 64 + srow;                                                  \
            const int ls = ((sslot ^ (r & 7)) * 8);                                       \
            __builtin_amdgcn_global_load_lds(                                             \
                (const AS1 unsigned*)(Bg + (size_t)r * HIDDEN + ls),                      \
                (AS3 unsigned*)(&LDS[(bf) * 2 + 1][j * 4096 + wid * 512]), 16, 0, 0);     \
        }                                                                                 \
    }

    STAGE(0, 0);
    STAGE(1, 1);

    int cur = 0;
    for (int kt = 0; kt < 16; ++kt) {
        if (kt < 15) { asm volatile("s_waitcnt vmcnt(8)" ::: "memory"); }
        else         { asm volatile("s_waitcnt vmcnt(0)" ::: "memory"); }
        __builtin_amdgcn_s_barrier();          // whole tile bf=cur visible to all waves

        const unsigned short* Ab = &LDS[cur * 2 + 0][0];
        const unsigned short* Bb = &LDS[cur * 2 + 1][0];
        bf16x8 af[8][2], bg[4][2];
#pragma unroll
        for (int mi = 0; mi < 8; ++mi) {
            const int ra = wr * 128 + mi * 16 + fr;
#pragma unroll
            for (int ks = 0; ks < 2; ++ks)
                af[mi][ks] = *(const bf16x8*)&Ab[ra * 64 + (((ks * 4 + fq) ^ (fr & 7)) * 8)];
        }
#pragma unroll
        for (int ni = 0; ni < 4; ++ni) {
            const int rb = wc * 64 + ni * 16 + fr;
#pragma unroll
            for (int ks = 0; ks < 2; ++ks)
                bg[ni][ks] = *(const bf16x8*)&Bb[rb * 64 + (((ks * 4 + fq) ^ (fr & 7)) * 8)];
        }
        asm volatile("s_waitcnt lgkmcnt(0)" ::: "memory");
        __builtin_amdgcn_sched_barrier(0);
        __builtin_amdgcn_s_barrier();          // all waves done reading bf=cur

        if (kt < 14) STAGE(kt + 2, cur);       // overwrite freed buffer; stays in flight

        __builtin_amdgcn_s_setprio(1);
#pragma unroll
        for (int mi = 0; mi < 8; ++mi)
#pragma unroll
            for (int ni = 0; ni < 4; ++ni) {
                acc[mi][ni] = __builtin_amdgcn_mfma_f32_16x16x32_bf16(af[mi][0], bg[ni][0], acc[mi][ni], 0, 0, 0);
                acc[mi][ni] = __builtin_amdgcn_mfma_f32_16x16x32_bf16(af[mi][1], bg[ni][1], acc[mi][ni], 0, 0, 0);
            }
        __builtin_amdgcn_s_setprio(0);
        cur ^= 1;
    }
#undef STAGE

#pragma unroll
    for (int ni = 0; ni < 4; ++ni) {
        const int col = n0 + wc * 64 + ni * 16 + fr;
        const float bias = by[col];
#pragma unroll
        for (int mi = 0; mi < 8; ++mi) {
            const int row = m0 + wr * 128 + mi * 16 + fq * 4;
            float* cp = C + (size_t)row * VOCAB + col;
            cp[0]                 = acc[mi][ni][0] + bias;
            cp[(size_t)VOCAB]     = acc[mi][ni][1] + bias;
            cp[(size_t)2 * VOCAB] = acc[mi][ni][2] + bias;
            cp[(size_t)3 * VOCAB] = acc[mi][ni][3] + bias;
        }
    }
}

extern "C" void kernel_launch(void* const* d_in, const int* in_sizes, int n_in,
                              void* d_out, int out_size, void* d_ws, size_t ws_size,
                              hipStream_t stream) {
    const int*   x   = (const int*)d_in[0];
    const float* emb = (const float*)d_in[1];
    const float* Wxh = (const float*)d_in[2];
    const float* Whh = (const float*)d_in[3];
    const float* bh  = (const float*)d_in[4];
    const float* Why = (const float*)d_in[5];
    const float* by  = (const float*)d_in[6];
    float* y = (float*)d_out;

    char* ws = (char*)d_ws;
    // layout: xh (8 MB) | hx u64[8][2][512] (64 KB) | hs bf16 (4 MB) | Wt bf16 (62.5 MB)
    const size_t off_xh = 0;
    const size_t off_hx = off_xh + (size_t)NB * NT * HIDDEN * 4;
    const size_t off_hs = off_hx + (size_t)NCH * 2 * 512 * 8;
    const size_t off_wt = off_hs + (size_t)NB * NT * HIDDEN * 2;
    const size_t need   = off_wt + (size_t)VOCAB * HIDDEN * 2;
    if (ws_size < need) return;

    float* xh = (float*)(ws + off_xh);
    unsigned long long* hx = (unsigned long long*)(ws + off_hx);
    __hip_bfloat16* hs = (__hip_bfloat16*)(ws + off_hs);
    __hip_bfloat16* Wt = (__hip_bfloat16*)(ws + off_wt);

    k_xh<<<dim3((NB * NT) / XH_ROWS), 256, 0, stream>>>(x, emb, Wxh, bh, xh);
    k_transpose<<<dim3(VOCAB / 32, HIDDEN / 32), 256, 0, stream>>>(Why, Wt);
    k_rec<<<dim3(NCH * NMEM), 256, 0, stream>>>(Whh, xh, hx, hs);
    k_proj<<<dim3((2048 / 256) * (VOCAB / 256)), 512, 0, stream>>>((const unsigned short*)hs,
                                                                   (const unsigned short*)Wt, by, y);
}